// Round 1
// baseline (468.126 us; speedup 1.0000x reference)
//
#include <hip/hip_runtime.h>

#define T_TOK 16384
#define D_DIM 4096
#define E_EXP 128
#define CAP   256
#define ROWS  32
#define KC    32

// ---------------------------------------------------------------------------
// Kernel A: fused GEMM (logits = x @ wg^T) + top2 + softmax + me partial sums
// Block: 256 threads, 32 rows x 128 experts. fp32 FMA per K-chunk, fp64
// chunk accumulation for tie-flip safety vs the numpy reference.
// ---------------------------------------------------------------------------
__global__ __launch_bounds__(256) void gemm_gate_kernel(
    const float* __restrict__ x, const float* __restrict__ wg,
    float* __restrict__ out, float* __restrict__ me)
{
    __shared__ float xs[ROWS][KC + 1];
    __shared__ float wgs[E_EXP][KC + 1];
    __shared__ float lg[ROWS][E_EXP + 1];

    const int tid  = threadIdx.x;
    const int row0 = blockIdx.x * ROWS;
    const int er   = tid & 31;   // expert group: experts {er, er+32, er+64, er+96}
    const int rw   = tid >> 5;   // row group:    rows    {4rw .. 4rw+3}

    double acc[4][4];
#pragma unroll
    for (int i = 0; i < 4; i++)
#pragma unroll
        for (int j = 0; j < 4; j++) acc[i][j] = 0.0;

    const int lr = tid >> 3;        // 0..31
    const int lc = (tid & 7) * 4;   // 0,4,..28

    for (int d0 = 0; d0 < D_DIM; d0 += KC) {
        const float4 xv4 = *reinterpret_cast<const float4*>(
            &x[(size_t)(row0 + lr) * D_DIM + d0 + lc]);
        float4 wv4[4];
#pragma unroll
        for (int p = 0; p < 4; p++)
            wv4[p] = *reinterpret_cast<const float4*>(
                &wg[(size_t)(p * 32 + lr) * D_DIM + d0 + lc]);

        __syncthreads();   // previous iteration's LDS reads done
        xs[lr][lc + 0] = xv4.x; xs[lr][lc + 1] = xv4.y;
        xs[lr][lc + 2] = xv4.z; xs[lr][lc + 3] = xv4.w;
#pragma unroll
        for (int p = 0; p < 4; p++) {
            wgs[p * 32 + lr][lc + 0] = wv4[p].x;
            wgs[p * 32 + lr][lc + 1] = wv4[p].y;
            wgs[p * 32 + lr][lc + 2] = wv4[p].z;
            wgs[p * 32 + lr][lc + 3] = wv4[p].w;
        }
        __syncthreads();

        float ch[4][4];
#pragma unroll
        for (int i = 0; i < 4; i++)
#pragma unroll
            for (int j = 0; j < 4; j++) ch[i][j] = 0.0f;

#pragma unroll 8
        for (int d = 0; d < KC; d++) {
            float xr[4], wr[4];
#pragma unroll
            for (int i = 0; i < 4; i++) xr[i] = xs[rw * 4 + i][d];
#pragma unroll
            for (int j = 0; j < 4; j++) wr[j] = wgs[er + 32 * j][d];
#pragma unroll
            for (int i = 0; i < 4; i++)
#pragma unroll
                for (int j = 0; j < 4; j++)
                    ch[i][j] = fmaf(xr[i], wr[j], ch[i][j]);
        }
#pragma unroll
        for (int i = 0; i < 4; i++)
#pragma unroll
            for (int j = 0; j < 4; j++) acc[i][j] += (double)ch[i][j];
    }

    __syncthreads();
#pragma unroll
    for (int i = 0; i < 4; i++)
#pragma unroll
        for (int j = 0; j < 4; j++)
            lg[rw * 4 + i][er + 32 * j] = (float)acc[i][j];
    __syncthreads();

    if (tid < ROWS) {
        const int r = tid;
        const int t = row0 + r;
        float m1 = -1e30f, m2 = -1e30f;
        int   i1 = 0, i2 = 0;
        for (int e = 0; e < E_EXP; e++) {
            float v = lg[r][e];
            if (v > m1)      { m2 = m1; i2 = i1; m1 = v; i1 = e; }
            else if (v > m2) { m2 = v; i2 = e; }
        }
        float s = 0.0f;
        for (int e = 0; e < E_EXP; e++) s += __expf(lg[r][e] - m1);
        const float inv = 1.0f / s;

        out[3 + 0 * T_TOK + t] = (float)i1;            // idx1
        out[3 + 1 * T_TOK + t] = (float)i2;            // idx2
        out[3 + 4 * T_TOK + t] = inv;                  // gates1_s = exp(0)/s
        out[3 + 5 * T_TOK + t] = __expf(m2 - m1) * inv; // gates2_s

        for (int e = 0; e < E_EXP; e++)
            lg[r][e] = __expf(lg[r][e] - m1) * inv;    // gates row
    }
    __syncthreads();

    if (tid < E_EXP) {
        float s = 0.0f;
        for (int r = 0; r < ROWS; r++) s += lg[r][tid];
        atomicAdd(&me[tid], s);
    }
}

// ---------------------------------------------------------------------------
// Kernel B: per-expert rank (cumsum) for locations1_s / locations2_s + ce.
// One block per expert; ballot-based block-wide exclusive scan in token order.
// ---------------------------------------------------------------------------
__global__ __launch_bounds__(256) void rank_kernel(
    float* __restrict__ out, float* __restrict__ ce)
{
    const int e    = blockIdx.x;
    const int tid  = threadIdx.x;
    const int lane = tid & 63;
    const int w    = tid >> 6;

    __shared__ int wtot[4];

    const float* idx1 = out + 3;
    const float* idx2 = out + 3 + T_TOK;
    float* loc1 = out + 3 + 2 * T_TOK;
    float* loc2 = out + 3 + 3 * T_TOK;

    const unsigned long long below = (1ull << lane) - 1ull;
    int base = 0;

    // phase 1: idx1 ranks
    for (int t0 = 0; t0 < T_TOK; t0 += 256) {
        const int t = t0 + tid;
        const int f = ((int)idx1[t] == e);
        const unsigned long long m = __ballot(f);
        const int pre = __popcll(m & below);
        const int tot = __popcll(m);
        if (lane == 0) wtot[w] = tot;
        __syncthreads();
        int off = 0;
        for (int i = 0; i < w; i++) off += wtot[i];
        const int all = wtot[0] + wtot[1] + wtot[2] + wtot[3];
        if (f) {
            const int rank = base + off + pre;
            loc1[t] = (rank < CAP) ? (float)rank : 0.0f;
        }
        base += all;
        __syncthreads();
    }

    const int count1 = base;
    if (tid == 0) ce[e] = (float)((count1 < CAP) ? count1 : CAP);

    // phase 2: idx2 ranks, offset by count1 (base already == count1)
    for (int t0 = 0; t0 < T_TOK; t0 += 256) {
        const int t = t0 + tid;
        const int f = ((int)idx2[t] == e);
        const unsigned long long m = __ballot(f);
        const int pre = __popcll(m & below);
        const int tot = __popcll(m);
        if (lane == 0) wtot[w] = tot;
        __syncthreads();
        int off = 0;
        for (int i = 0; i < w; i++) off += wtot[i];
        const int all = wtot[0] + wtot[1] + wtot[2] + wtot[3];
        if (f) {
            const int rank = base + off + pre;
            loc2[t] = (rank < CAP) ? (float)rank : 0.0f;
        }
        base += all;
        __syncthreads();
    }
}

// ---------------------------------------------------------------------------
// Kernel C: l_aux = sum(me*ce) * E/(T*T); also write capacity and E.
// ---------------------------------------------------------------------------
__global__ __launch_bounds__(128) void finalize_kernel(
    const float* __restrict__ me, const float* __restrict__ ce,
    float* __restrict__ out)
{
    __shared__ float red[2];
    const int tid = threadIdx.x;   // 128 threads
    float p = me[tid] * ce[tid];
#pragma unroll
    for (int o = 32; o > 0; o >>= 1) p += __shfl_down(p, o);
    if ((tid & 63) == 0) red[tid >> 6] = p;
    __syncthreads();
    if (tid == 0) {
        const float tot = red[0] + red[1];
        out[0] = tot * ((float)E_EXP / ((float)T_TOK * (float)T_TOK));
        out[1] = (float)CAP;    // capacity
        out[2] = (float)E_EXP;  // E
    }
}

extern "C" void kernel_launch(void* const* d_in, const int* in_sizes, int n_in,
                              void* d_out, int out_size, void* d_ws, size_t ws_size,
                              hipStream_t stream)
{
    const float* x  = (const float*)d_in[0];
    const float* wg = (const float*)d_in[1];
    float* out = (float*)d_out;
    float* me  = (float*)d_ws;     // 128 floats
    float* ce  = me + 128;         // 128 floats

    hipMemsetAsync(me, 0, 128 * sizeof(float), stream);
    gemm_gate_kernel<<<T_TOK / ROWS, 256, 0, stream>>>(x, wg, out, me);
    rank_kernel<<<E_EXP, 256, 0, stream>>>(out, ce);
    finalize_kernel<<<1, 128, 0, stream>>>(me, ce, out);
}

// Round 2
// 236.539 us; speedup vs baseline: 1.9791x; 1.9791x over previous
//
#include <hip/hip_runtime.h>

typedef _Float16 half8 __attribute__((ext_vector_type(8)));
typedef _Float16 half4 __attribute__((ext_vector_type(4)));
typedef float    f32x4 __attribute__((ext_vector_type(4)));

#define T_TOK 16384
#define D_DIM 4096
#define E_EXP 128
#define CAP   256
#define BM    64
#define BK    32
#define NT    (D_DIM / BK)   // 128 K-steps

// LDS geometry (bytes). Row stride 80 = 5*16B keeps ds_read_b128 frag reads
// conflict-free (<=2-way bank aliasing, free per m136).
#define A_ROW_STR 80
#define A_COMP    (BM * A_ROW_STR)      // 5120
#define A_BUF     (2 * A_COMP)          // 10240 (h,m components)
#define B_ROW_STR 80
#define B_COMP    (E_EXP * B_ROW_STR)   // 10240
#define B_BUF     (2 * B_COMP)          // 20480
#define A_REGION  (2 * A_BUF)           // 20480 (double buffer)
#define SMEM_BYTES (A_REGION + 2 * B_BUF)  // 61440; logits alias needs 33024

// ---------------------------------------------------------------------------
// Kernel 0: wg (fp32) -> scaled split-fp16 planes. w64 = wg*64 (exact pow2
// rescale keeps w_m in fp16 normal range); h = fp16(w64), m = fp16(w64 - h).
// ---------------------------------------------------------------------------
__global__ __launch_bounds__(256) void prep_wg(
    const float* __restrict__ wg, _Float16* __restrict__ wh,
    _Float16* __restrict__ wm)
{
    const int i = (blockIdx.x * 256 + threadIdx.x) * 4;
    const f32x4 v = *reinterpret_cast<const f32x4*>(wg + i);
    half4 h, m;
#pragma unroll
    for (int j = 0; j < 4; j++) {
        const float s = v[j] * 64.0f;
        const _Float16 hh = (_Float16)s;
        h[j] = hh;
        m[j] = (_Float16)(s - (float)hh);
    }
    *reinterpret_cast<half4*>(wh + i) = h;
    *reinterpret_cast<half4*>(wm + i) = m;
}

// ---------------------------------------------------------------------------
// Kernel A: split-fp16 MFMA GEMM (logits = x @ wg^T / 64) + top2 + softmax
// + me partial sums. 512 thr = 8 waves (2 row x 4 col), wave tile 32x32.
// ---------------------------------------------------------------------------
__global__ __launch_bounds__(512) void gemm_gate(
    const float* __restrict__ x, const _Float16* __restrict__ wh,
    const _Float16* __restrict__ wm, float* __restrict__ out,
    float* __restrict__ me)
{
    __shared__ char smem[SMEM_BYTES];

    const int tid  = threadIdx.x;
    const int row0 = blockIdx.x * BM;
    const int lane = tid & 63;
    const int wid  = tid >> 6;
    const int wrow = wid >> 2;   // 0..1
    const int wcol = wid & 3;    // 0..3
    const int lq   = lane >> 4;  // kspan 0..3 (8 halfs each)
    const int lr   = lane & 15;  // row/col within fragment

    // staging roles
    const int arow = tid >> 3;   // 0..63  (x row in tile)
    const int aq   = tid & 7;    // k-quad (4 fp32)
    const int be   = tid >> 2;   // 0..127 (expert)
    const int bq   = tid & 3;    // k-oct  (8 fp16)

    const float*    xg  = x  + (size_t)(row0 + arow) * D_DIM + aq * 4;
    const _Float16* whg = wh + (size_t)be * D_DIM + bq * 8;
    const _Float16* wmg = wm + (size_t)be * D_DIM + bq * 8;

    char* const sm = smem;
    const int aw_off = arow * A_ROW_STR + ((aq >> 1) * 16) + ((aq & 1) * 8);
    const int bw_off = A_REGION + be * B_ROW_STR + bq * 16;
    const int a_rd   = (32 * wrow + lr) * A_ROW_STR + lq * 16;
    const int b_rd   = A_REGION + (32 * wcol + lr) * B_ROW_STR + lq * 16;

    f32x4 acc[2][2];
#pragma unroll
    for (int i = 0; i < 2; i++)
#pragma unroll
        for (int j = 0; j < 2; j++) acc[i][j] = (f32x4)0.0f;

    // ---- prologue: stage tile 0 into buffer 0 ----
    {
        const f32x4 xv = *reinterpret_cast<const f32x4*>(xg);
        const half8 hv = *reinterpret_cast<const half8*>(whg);
        const half8 mv = *reinterpret_cast<const half8*>(wmg);
        half4 xh, xm;
#pragma unroll
        for (int j = 0; j < 4; j++) {
            const float s = xv[j];
            const _Float16 hh = (_Float16)s;
            xh[j] = hh;
            xm[j] = (_Float16)(s - (float)hh);
        }
        char* ab = sm + aw_off;
        *reinterpret_cast<half4*>(ab)          = xh;
        *reinterpret_cast<half4*>(ab + A_COMP) = xm;
        char* bb = sm + bw_off;
        *reinterpret_cast<half8*>(bb)          = hv;
        *reinterpret_cast<half8*>(bb + B_COMP) = mv;
    }
    __syncthreads();

    // ---- main K loop: one barrier per step, double-buffered ----
    for (int t = 0; t < NT; ++t) {
        const int buf = t & 1;

        f32x4 xv; half8 hv, mv;
        const bool pf = (t + 1 < NT);
        if (pf) {
            const int k0 = (t + 1) * BK;
            xv = *reinterpret_cast<const f32x4*>(xg + k0);
            hv = *reinterpret_cast<const half8*>(whg + k0);
            mv = *reinterpret_cast<const half8*>(wmg + k0);
        }

        const char* abase = sm + buf * A_BUF + a_rd;
        const char* bbase = sm + buf * B_BUF + b_rd;
        half8 Ah[2], Am[2], Bh[2], Bm[2];
#pragma unroll
        for (int rf = 0; rf < 2; rf++) {
            Ah[rf] = *reinterpret_cast<const half8*>(abase + rf * (16 * A_ROW_STR));
            Am[rf] = *reinterpret_cast<const half8*>(abase + rf * (16 * A_ROW_STR) + A_COMP);
        }
#pragma unroll
        for (int cf = 0; cf < 2; cf++) {
            Bh[cf] = *reinterpret_cast<const half8*>(bbase + cf * (16 * B_ROW_STR));
            Bm[cf] = *reinterpret_cast<const half8*>(bbase + cf * (16 * B_ROW_STR) + B_COMP);
        }

#pragma unroll
        for (int rf = 0; rf < 2; rf++)
#pragma unroll
            for (int cf = 0; cf < 2; cf++) {
                acc[rf][cf] = __builtin_amdgcn_mfma_f32_16x16x32_f16(Am[rf], Bm[cf], acc[rf][cf], 0, 0, 0);
                acc[rf][cf] = __builtin_amdgcn_mfma_f32_16x16x32_f16(Am[rf], Bh[cf], acc[rf][cf], 0, 0, 0);
                acc[rf][cf] = __builtin_amdgcn_mfma_f32_16x16x32_f16(Ah[rf], Bm[cf], acc[rf][cf], 0, 0, 0);
                acc[rf][cf] = __builtin_amdgcn_mfma_f32_16x16x32_f16(Ah[rf], Bh[cf], acc[rf][cf], 0, 0, 0);
            }

        if (pf) {
            half4 xh, xm;
#pragma unroll
            for (int j = 0; j < 4; j++) {
                const float s = xv[j];
                const _Float16 hh = (_Float16)s;
                xh[j] = hh;
                xm[j] = (_Float16)(s - (float)hh);
            }
            char* ab = sm + (buf ^ 1) * A_BUF + aw_off;
            *reinterpret_cast<half4*>(ab)          = xh;
            *reinterpret_cast<half4*>(ab + A_COMP) = xm;
            char* bb = sm + (buf ^ 1) * B_BUF + bw_off;
            *reinterpret_cast<half8*>(bb)          = hv;
            *reinterpret_cast<half8*>(bb + B_COMP) = mv;
        }
        __syncthreads();
    }

    // ---- epilogue: logits -> LDS (alias staging buffers), scale by 1/64 ----
    float* lg = reinterpret_cast<float*>(smem);  // [64][129]
#pragma unroll
    for (int rf = 0; rf < 2; rf++)
#pragma unroll
        for (int cf = 0; cf < 2; cf++)
#pragma unroll
            for (int r = 0; r < 4; r++) {
                const int row = 32 * wrow + 16 * rf + lq * 4 + r;
                const int col = 32 * wcol + 16 * cf + lr;
                lg[row * 129 + col] = acc[rf][cf][r] * 0.015625f;
            }
    __syncthreads();

    if (tid < BM) {
        const int r = tid;
        const int t = row0 + r;
        float m1 = -1e30f, m2 = -1e30f;
        int   i1 = 0, i2 = 0;
        for (int e = 0; e < E_EXP; e++) {
            const float v = lg[r * 129 + e];
            if (v > m1)      { m2 = m1; i2 = i1; m1 = v; i1 = e; }
            else if (v > m2) { m2 = v; i2 = e; }
        }
        float s = 0.0f;
        for (int e = 0; e < E_EXP; e++) s += __expf(lg[r * 129 + e] - m1);
        const float inv = 1.0f / s;

        out[3 + 0 * T_TOK + t] = (float)i1;
        out[3 + 1 * T_TOK + t] = (float)i2;
        out[3 + 4 * T_TOK + t] = inv;
        out[3 + 5 * T_TOK + t] = __expf(m2 - m1) * inv;

        for (int e = 0; e < E_EXP; e++)
            lg[r * 129 + e] = __expf(lg[r * 129 + e] - m1) * inv;
    }
    __syncthreads();

    if (tid < E_EXP) {
        float s = 0.0f;
        for (int r = 0; r < BM; r++) s += lg[r * 129 + tid];
        atomicAdd(&me[tid], s);
    }
}

// ---------------------------------------------------------------------------
// Kernel B: per-expert rank (cumsum) for locations1_s / locations2_s + ce.
// ---------------------------------------------------------------------------
__global__ __launch_bounds__(256) void rank_kernel(
    float* __restrict__ out, float* __restrict__ ce)
{
    const int e    = blockIdx.x;
    const int tid  = threadIdx.x;
    const int lane = tid & 63;
    const int w    = tid >> 6;

    __shared__ int wtot[4];

    const float* idx1 = out + 3;
    const float* idx2 = out + 3 + T_TOK;
    float* loc1 = out + 3 + 2 * T_TOK;
    float* loc2 = out + 3 + 3 * T_TOK;

    const unsigned long long below = (1ull << lane) - 1ull;
    int base = 0;

    for (int t0 = 0; t0 < T_TOK; t0 += 256) {
        const int t = t0 + tid;
        const int f = ((int)idx1[t] == e);
        const unsigned long long m = __ballot(f);
        const int pre = __popcll(m & below);
        const int tot = __popcll(m);
        if (lane == 0) wtot[w] = tot;
        __syncthreads();
        int off = 0;
        for (int i = 0; i < w; i++) off += wtot[i];
        const int all = wtot[0] + wtot[1] + wtot[2] + wtot[3];
        if (f) {
            const int rank = base + off + pre;
            loc1[t] = (rank < CAP) ? (float)rank : 0.0f;
        }
        base += all;
        __syncthreads();
    }

    const int count1 = base;
    if (tid == 0) ce[e] = (float)((count1 < CAP) ? count1 : CAP);

    for (int t0 = 0; t0 < T_TOK; t0 += 256) {
        const int t = t0 + tid;
        const int f = ((int)idx2[t] == e);
        const unsigned long long m = __ballot(f);
        const int pre = __popcll(m & below);
        const int tot = __popcll(m);
        if (lane == 0) wtot[w] = tot;
        __syncthreads();
        int off = 0;
        for (int i = 0; i < w; i++) off += wtot[i];
        const int all = wtot[0] + wtot[1] + wtot[2] + wtot[3];
        if (f) {
            const int rank = base + off + pre;
            loc2[t] = (rank < CAP) ? (float)rank : 0.0f;
        }
        base += all;
        __syncthreads();
    }
}

// ---------------------------------------------------------------------------
// Kernel C: l_aux = sum(me*ce) * E/(T*T); plus capacity and E constants.
// ---------------------------------------------------------------------------
__global__ __launch_bounds__(128) void finalize_kernel(
    const float* __restrict__ me, const float* __restrict__ ce,
    float* __restrict__ out)
{
    __shared__ float red[2];
    const int tid = threadIdx.x;
    float p = me[tid] * ce[tid];
#pragma unroll
    for (int o = 32; o > 0; o >>= 1) p += __shfl_down(p, o);
    if ((tid & 63) == 0) red[tid >> 6] = p;
    __syncthreads();
    if (tid == 0) {
        const float tot = red[0] + red[1];
        out[0] = tot * ((float)E_EXP / ((float)T_TOK * (float)T_TOK));
        out[1] = (float)CAP;
        out[2] = (float)E_EXP;
    }
}

extern "C" void kernel_launch(void* const* d_in, const int* in_sizes, int n_in,
                              void* d_out, int out_size, void* d_ws, size_t ws_size,
                              hipStream_t stream)
{
    const float* x  = (const float*)d_in[0];
    const float* wg = (const float*)d_in[1];
    float* out = (float*)d_out;

    float* me = (float*)d_ws;            // 128 floats
    float* ce = me + 128;                // 128 floats
    _Float16* wh = (_Float16*)((char*)d_ws + 1024);            // 1 MB
    _Float16* wm = wh + (size_t)E_EXP * D_DIM;                 // 1 MB

    hipMemsetAsync(me, 0, 128 * sizeof(float), stream);
    prep_wg<<<(E_EXP * D_DIM) / (256 * 4), 256, 0, stream>>>(wg, wh, wm);
    gemm_gate<<<T_TOK / BM, 512, 0, stream>>>(x, wh, wm, out, me);
    rank_kernel<<<E_EXP, 256, 0, stream>>>(out, ce);
    finalize_kernel<<<1, 128, 0, stream>>>(me, ce, out);
}